// Round 10
// baseline (478.533 us; speedup 1.0000x reference)
//
#include <hip/hip_runtime.h>
#include <hip/hip_bf16.h>

// GCN: 3x GCNConv (sym-norm, self-loops) + linear head.
// N=50000 nodes, E=800000 edges, F: 128 -> 128 -> 128 -> 64 -> 1.
// Round 10: break the cross-XCD gather-traffic floor (8 XCDs x 12.8 MB =
// 102 MB; measured 113 MB) by XCD-panel partitioning:
//   t' stored as 8 column-panels [N][16] bf16 (1.6 MB each -- fits one XCD's
//   4 MB L2). panel = blockIdx.x & 7 rides the round-robin block->XCD map so
//   XCD p only touches panel p; gathers become L2 hits.
//   One wave per (node,panel): 4 lanes/row x 16 edge groups = 16 rows in
//   flight per load instr; shfl_xor reduce across edge groups.
//   GEMM epilogue writes panels directly (16-col groups panel-aligned).
//   F=64 layer: 4 panels; head un-fused into a tiny dot kernel.
// Perf heuristic only -- wrong XCD mapping degrades to round-9 behavior.
// CSR build + gemm core unchanged from round 9.

#define N_NODES 50000
#define N_EDGES 800000
#define NBUCK 196          // ceil(N/256) coarse buckets (dst>>8)
#define GB 196             // edge-chunk blocks
#define EPB 4096           // edges per block (GB*EPB >= E)

typedef __attribute__((ext_vector_type(8))) short short8;   // 8 bf16 = 4 VGPR
typedef __attribute__((ext_vector_type(4))) float f32x4;    // MFMA C/D

static __device__ __forceinline__ unsigned short f2bf(float f) {
    __hip_bfloat16 h = __float2bfloat16(f);  // RNE
    return *reinterpret_cast<unsigned short*>(&h);
}
static __device__ __forceinline__ float bf2f(unsigned short u) {
    return __uint_as_float(((unsigned)u) << 16);  // exact
}

// ---------- CSR build: two-level counting sort ----------

__global__ __launch_bounds__(256) void hist_kernel(const int* __restrict__ dstv,
                                                   int* __restrict__ H, int nE) {
    __shared__ int h[NBUCK];
    for (int i = threadIdx.x; i < NBUCK; i += 256) h[i] = 0;
    __syncthreads();
    int base = blockIdx.x * EPB;
#pragma unroll
    for (int i = 0; i < EPB / 256; ++i) {
        int e = base + i * 256 + threadIdx.x;
        if (e < nE) atomicAdd(&h[dstv[e] >> 8], 1);
    }
    __syncthreads();
    for (int i = threadIdx.x; i < NBUCK; i += 256)
        H[i * GB + blockIdx.x] = h[i];   // bucket-major
}

__global__ __launch_bounds__(256) void scan1_kernel(int* __restrict__ H,
                                                    int* __restrict__ bsum) {
    __shared__ int s[256];
    int t = threadIdx.x;
    int k = blockIdx.x;
    int v = (t < GB) ? H[k * GB + t] : 0;
    s[t] = v;
    __syncthreads();
    for (int off = 1; off < 256; off <<= 1) {
        int u = (t >= off) ? s[t - off] : 0;
        __syncthreads();
        s[t] += u;
        __syncthreads();
    }
    if (t < GB) H[k * GB + t] = s[t] - v;  // local exclusive
    if (t == 255) bsum[k] = s[255];
}

__global__ __launch_bounds__(256) void scan2_kernel(const int* __restrict__ bsum,
                                                    int* __restrict__ bstart,
                                                    int* __restrict__ rowoff_last) {
    __shared__ int s[256];
    int t = threadIdx.x;
    int v = (t < NBUCK) ? bsum[t] : 0;
    s[t] = v;
    __syncthreads();
    for (int off = 1; off < 256; off <<= 1) {
        int u = (t >= off) ? s[t - off] : 0;
        __syncthreads();
        s[t] += u;
        __syncthreads();
    }
    if (t < NBUCK) bstart[t] = s[t] - v;  // exclusive
    if (t == 0) {
        bstart[NBUCK] = N_EDGES;
        *rowoff_last = N_EDGES;
    }
}

__global__ __launch_bounds__(256) void partition_kernel(const int* __restrict__ srcv,
                                                        const int* __restrict__ dstv,
                                                        const int* __restrict__ H,
                                                        const int* __restrict__ bstart,
                                                        int2* __restrict__ P, int nE) {
    __shared__ int cur[NBUCK];
    for (int i = threadIdx.x; i < NBUCK; i += 256)
        cur[i] = bstart[i] + H[i * GB + blockIdx.x];
    __syncthreads();
    int base = blockIdx.x * EPB;
#pragma unroll
    for (int i = 0; i < EPB / 256; ++i) {
        int e = base + i * 256 + threadIdx.x;
        if (e < nE) {
            int d = dstv[e];
            int sv = srcv[e];
            int pos = atomicAdd(&cur[d >> 8], 1);
            P[pos] = make_int2(sv, d);
        }
    }
}

__global__ __launch_bounds__(256) void bucket_csr_kernel(const int2* __restrict__ P,
                                                         const int* __restrict__ bstart,
                                                         int* __restrict__ rowoff,
                                                         float* __restrict__ dis,
                                                         int* __restrict__ csr_src, int n) {
    __shared__ int cnt[256];
    __shared__ int s[256];
    __shared__ int cur[256];
    int t = threadIdx.x;
    int k = blockIdx.x;
    int ebeg = bstart[k], eend = bstart[k + 1];
    cnt[t] = 0;
    __syncthreads();
    for (int e = ebeg + t; e < eend; e += 256)
        atomicAdd(&cnt[P[e].y & 255], 1);
    __syncthreads();
    int myc = cnt[t];
    s[t] = myc;
    __syncthreads();
    for (int off = 1; off < 256; off <<= 1) {
        int v = (t >= off) ? s[t - off] : 0;
        __syncthreads();
        s[t] += v;
        __syncthreads();
    }
    int excl = s[t] - myc;
    int node = (k << 8) + t;
    if (node < n) {
        rowoff[node] = ebeg + excl;
        dis[node] = rsqrtf((float)(myc + 1));  // +1 self-loop
    }
    cur[t] = ebeg + excl;
    __syncthreads();
    for (int e = ebeg + t; e < eend; e += 256) {
        int2 p = P[e];
        int pos = atomicAdd(&cur[p.y & 255], 1);
        csr_src[pos] = p.x;
    }
}

// ---------- W prep (fused): W -> transposed bf16 hi/lo [col][k] ----------
__global__ __launch_bounds__(256) void wprep_all_kernel(
    const float* __restrict__ W1, const float* __restrict__ Wh, const float* __restrict__ W2,
    unsigned short* __restrict__ W1hi, unsigned short* __restrict__ W1lo,
    unsigned short* __restrict__ Whhi, unsigned short* __restrict__ Whlo,
    unsigned short* __restrict__ W2hi, unsigned short* __restrict__ W2lo) {
    int t = blockIdx.x * 256 + threadIdx.x;
    const float* W;
    unsigned short *Hi, *Lo;
    int nout, lt;
    if (t < 16384)      { W = W1; Hi = W1hi; Lo = W1lo; nout = 128; lt = t; }
    else if (t < 32768) { W = Wh; Hi = Whhi; Lo = Whlo; nout = 128; lt = t - 16384; }
    else if (t < 40960) { W = W2; Hi = W2hi; Lo = W2lo; nout = 64;  lt = t - 32768; }
    else return;
    int col = lt % nout, k = lt / nout;
    float v = W[lt];                       // coalesced (lt == k*nout+col)
    unsigned short hi = f2bf(v);
    unsigned short lo = f2bf(v - bf2f(hi));
    Hi[(size_t)col * 128 + k] = hi;
    Lo[(size_t)col * 128 + k] = lo;
}

// ---------- MFMA GEMM: panel-layout out: C = 16-col panels [N][16] bf16 ----
// Block = 64 rows x 64 cols, 4 waves. B hi/lo in registers, A hi/lo in LDS.
template <int NOUT>
__global__ __launch_bounds__(256) void gemm_mfma_kernel(
    const float* __restrict__ A,
    const unsigned short* __restrict__ Wthi,  // [NOUT][128] bf16
    const unsigned short* __restrict__ Wtlo,
    const float* __restrict__ scale,
    unsigned short* __restrict__ C, int M) {
    constexpr int LDK = 136;  // shorts; 16 B-aligned frags, banks spread
    __shared__ unsigned short sAhi[64 * LDK];
    __shared__ unsigned short sAlo[64 * LDK];

    int tid = threadIdx.x;
    int w = tid >> 6, lane = tid & 63;
    int quad = lane >> 4, m = lane & 15;
    int Rbase = blockIdx.x * 64;
    int Cbase = blockIdx.y * 64;
    int r0 = (w & 1) * 32, c0 = (w >> 1) * 32;

    // B-frags to registers (once per wave): [ks][grp], grp = col 16-group
    short8 bh[4][2], bl[4][2];
#pragma unroll
    for (int ks = 0; ks < 4; ++ks)
#pragma unroll
        for (int g = 0; g < 2; ++g) {
            size_t off = (size_t)(Cbase + c0 + g * 16 + m) * 128 + ks * 32 + quad * 8;
            bh[ks][g] = *(const short8*)(Wthi + off);
            bl[ks][g] = *(const short8*)(Wtlo + off);
        }

    // stage A: 64 rows x 128 fp32 -> hi/lo bf16 in LDS
    for (int i = tid; i < 64 * 32; i += 256) {
        int r = i >> 5, c4 = i & 31;
        int row = Rbase + r;
        float4 v = make_float4(0.f, 0.f, 0.f, 0.f);
        if (row < M) v = ((const float4*)(A + (size_t)row * 128))[c4];
        ushort4 hi, lo;
        hi.x = f2bf(v.x); lo.x = f2bf(v.x - bf2f(hi.x));
        hi.y = f2bf(v.y); lo.y = f2bf(v.y - bf2f(hi.y));
        hi.z = f2bf(v.z); lo.z = f2bf(v.z - bf2f(hi.z));
        hi.w = f2bf(v.w); lo.w = f2bf(v.w - bf2f(hi.w));
        *(ushort4*)(sAhi + r * LDK + c4 * 4) = hi;
        *(ushort4*)(sAlo + r * LDK + c4 * 4) = lo;
    }
    __syncthreads();

    f32x4 z = {0.f, 0.f, 0.f, 0.f};
    f32x4 acc00 = z, acc01 = z, acc10 = z, acc11 = z;

#pragma unroll
    for (int ks = 0; ks < 4; ++ks) {
        int kof = ks * 32 + quad * 8;
        short8 ah0 = *(const short8*)(sAhi + (r0 + m) * LDK + kof);
        short8 ah1 = *(const short8*)(sAhi + (r0 + 16 + m) * LDK + kof);
        short8 al0 = *(const short8*)(sAlo + (r0 + m) * LDK + kof);
        short8 al1 = *(const short8*)(sAlo + (r0 + 16 + m) * LDK + kof);
        acc00 = __builtin_amdgcn_mfma_f32_16x16x32_bf16(ah0, bh[ks][0], acc00, 0, 0, 0);
        acc01 = __builtin_amdgcn_mfma_f32_16x16x32_bf16(ah0, bh[ks][1], acc01, 0, 0, 0);
        acc10 = __builtin_amdgcn_mfma_f32_16x16x32_bf16(ah1, bh[ks][0], acc10, 0, 0, 0);
        acc11 = __builtin_amdgcn_mfma_f32_16x16x32_bf16(ah1, bh[ks][1], acc11, 0, 0, 0);
        acc00 = __builtin_amdgcn_mfma_f32_16x16x32_bf16(ah0, bl[ks][0], acc00, 0, 0, 0);
        acc01 = __builtin_amdgcn_mfma_f32_16x16x32_bf16(ah0, bl[ks][1], acc01, 0, 0, 0);
        acc10 = __builtin_amdgcn_mfma_f32_16x16x32_bf16(ah1, bl[ks][0], acc10, 0, 0, 0);
        acc11 = __builtin_amdgcn_mfma_f32_16x16x32_bf16(ah1, bl[ks][1], acc11, 0, 0, 0);
        acc00 = __builtin_amdgcn_mfma_f32_16x16x32_bf16(al0, bh[ks][0], acc00, 0, 0, 0);
        acc01 = __builtin_amdgcn_mfma_f32_16x16x32_bf16(al0, bh[ks][1], acc01, 0, 0, 0);
        acc10 = __builtin_amdgcn_mfma_f32_16x16x32_bf16(al1, bh[ks][0], acc10, 0, 0, 0);
        acc11 = __builtin_amdgcn_mfma_f32_16x16x32_bf16(al1, bh[ks][1], acc11, 0, 0, 0);
    }

    // epilogue -> panel layout: panel pc = col/16, addr = pc*M*16 + row*16 + m
    unsigned short* pan0 = C + (size_t)((Cbase + c0) >> 4) * M * 16;
    unsigned short* pan1 = C + (size_t)((Cbase + c0 + 16) >> 4) * M * 16;
#pragma unroll
    for (int reg = 0; reg < 4; ++reg) {
        int row0g = Rbase + r0 + quad * 4 + reg;
        if (row0g < M) {
            float sc = scale[row0g];
            pan0[(size_t)row0g * 16 + m] = f2bf(acc00[reg] * sc);
            pan1[(size_t)row0g * 16 + m] = f2bf(acc01[reg] * sc);
        }
        int row1g = row0g + 16;
        if (row1g < M) {
            float sc = scale[row1g];
            pan0[(size_t)row1g * 16 + m] = f2bf(acc10[reg] * sc);
            pan1[(size_t)row1g * 16 + m] = f2bf(acc11[reg] * sc);
        }
    }
}

// ---------- Panel gather aggregation ----------
// tp: NPANEL panels [N][16] bf16. panel = blockIdx.x & (NPANEL-1) -> rides the
// round-robin block->XCD map so each XCD's L2 holds one ~1.6 MB panel.
// One wave per (node, panel): lane = eg*4 + cg; eg in [0,16) = edge group,
// cg in [0,4) = 4-col group. 16 gather rows in flight per load.
// h[node][p*16 + cg*4 ..] = maybe_relu(dd * (self + sum) + bias).
template <int NPANEL, bool RELU>
__global__ __launch_bounds__(256) void aggregate_panel_kernel(
    const int* __restrict__ rowoff, const int* __restrict__ csr_src,
    const float* __restrict__ dis, const unsigned short* __restrict__ tp,
    const float* __restrict__ bias, float* __restrict__ hout, int n) {
    constexpr int F = NPANEL * 16;
    int p = blockIdx.x & (NPANEL - 1);
    int node = (blockIdx.x / NPANEL) * 4 + (threadIdx.x >> 6);
    if (node >= n) return;
    int lane = threadIdx.x & 63;
    int eg = lane >> 2;
    int cg = lane & 3;
    const unsigned short* panel = tp + (size_t)p * n * 16;

    float ax = 0.f, ay = 0.f, az = 0.f, aw = 0.f;
    if (eg == 0) {  // self-loop row
        ushort4 u = *((const ushort4*)(panel + (size_t)node * 16) + cg);
        ax = bf2f(u.x); ay = bf2f(u.y); az = bf2f(u.z); aw = bf2f(u.w);
    }
    int beg = rowoff[node], end = rowoff[node + 1];
    for (int ib = beg; ib < end; ib += 16) {
        int e = ib + eg;
        if (e < end) {
            int s = csr_src[e];
            ushort4 u = *((const ushort4*)(panel + (size_t)s * 16) + cg);
            ax += bf2f(u.x); ay += bf2f(u.y); az += bf2f(u.z); aw += bf2f(u.w);
        }
    }
    // reduce across the 16 edge groups (lanes spaced by 4)
#pragma unroll
    for (int off = 4; off < 64; off <<= 1) {
        ax += __shfl_xor(ax, off);
        ay += __shfl_xor(ay, off);
        az += __shfl_xor(az, off);
        aw += __shfl_xor(aw, off);
    }
    if (eg == 0) {
        float dd = dis[node];
        float4 b = *((const float4*)(bias + p * 16) + cg);
        float4 r;
        r.x = ax * dd + b.x; r.y = ay * dd + b.y;
        r.z = az * dd + b.z; r.w = aw * dd + b.w;
        if (RELU) {
            r.x = fmaxf(r.x, 0.f); r.y = fmaxf(r.y, 0.f);
            r.z = fmaxf(r.z, 0.f); r.w = fmaxf(r.w, 0.f);
        }
        *((float4*)(hout + (size_t)node * F + p * 16) + cg) = r;
    }
}

// out[n] = dot(h3[n, 0:64], Wout) + bout ; one wave per node
__global__ __launch_bounds__(256) void head_kernel(const float* __restrict__ h3,
                                                   const float* __restrict__ Wout,
                                                   const float* __restrict__ bout,
                                                   float* __restrict__ out, int n) {
    int wave = (blockIdx.x * 256 + threadIdx.x) >> 6;
    int lane = threadIdx.x & 63;
    if (wave >= n) return;
    float v = h3[(size_t)wave * 64 + lane] * Wout[lane];
#pragma unroll
    for (int off = 32; off > 0; off >>= 1) v += __shfl_down(v, off);
    if (lane == 0) out[wave] = v + bout[0];
}

extern "C" void kernel_launch(void* const* d_in, const int* in_sizes, int n_in,
                              void* d_out, int out_size, void* d_ws, size_t ws_size,
                              hipStream_t stream) {
    const float* x    = (const float*)d_in[0];
    const int*   ei   = (const int*)d_in[1];  // [2, E] flat: src then dst
    const float* W1   = (const float*)d_in[2];
    const float* b1   = (const float*)d_in[3];
    const float* Wh   = (const float*)d_in[4];
    const float* bh   = (const float*)d_in[5];
    const float* W2   = (const float*)d_in[6];
    const float* b2   = (const float*)d_in[7];
    const float* Wout = (const float*)d_in[8];
    const float* bout = (const float*)d_in[9];

    const int N = N_NODES;
    const int E = N_EDGES;
    const int* srcv = ei;
    const int* dstv = ei + E;

    float* out  = (float*)d_out;            // [N]
    float* hout = (float*)d_out + N;        // [N x 64]

    char* ws = (char*)d_ws;
    int*   H       = (int*)ws;                          ws += sizeof(int) * NBUCK * GB;
    int*   bsum    = (int*)ws;                          ws += sizeof(int) * NBUCK;
    int*   bstart  = (int*)ws;                          ws += sizeof(int) * (NBUCK + 1);
    int*   rowoff  = (int*)ws;                          ws += sizeof(int) * (N + 1);
    int2*  P       = (int2*)ws;                         ws += sizeof(int2) * E;
    int*   csr_src = (int*)ws;                          ws += sizeof(int) * E;
    float* dis     = (float*)ws;                        ws += sizeof(float) * N;
    unsigned short* W1thi = (unsigned short*)ws;        ws += sizeof(unsigned short) * 128 * 128;
    unsigned short* W1tlo = (unsigned short*)ws;        ws += sizeof(unsigned short) * 128 * 128;
    unsigned short* Whthi = (unsigned short*)ws;        ws += sizeof(unsigned short) * 128 * 128;
    unsigned short* Whtlo = (unsigned short*)ws;        ws += sizeof(unsigned short) * 128 * 128;
    unsigned short* W2thi = (unsigned short*)ws;        ws += sizeof(unsigned short) * 64 * 128;
    unsigned short* W2tlo = (unsigned short*)ws;        ws += sizeof(unsigned short) * 64 * 128;
    unsigned short* bufT  = (unsigned short*)ws;        ws += sizeof(unsigned short) * (size_t)N * 128;
    float* bufH    = (float*)ws;                        // N*128 fp32

    // --- W prep (fused, bf16 hi/lo transposed) ---
    wprep_all_kernel<<<160, 256, 0, stream>>>(W1, Wh, W2, W1thi, W1tlo, Whthi, Whtlo, W2thi, W2tlo);

    // --- CSR build (two-level counting sort, hierarchical scan) ---
    hist_kernel<<<GB, 256, 0, stream>>>(dstv, H, E);
    scan1_kernel<<<NBUCK, 256, 0, stream>>>(H, bsum);
    scan2_kernel<<<1, 256, 0, stream>>>(bsum, bstart, rowoff + N);
    partition_kernel<<<GB, 256, 0, stream>>>(srcv, dstv, H, bstart, P, E);
    bucket_csr_kernel<<<NBUCK, 256, 0, stream>>>(P, bstart, rowoff, dis, csr_src, N);

    const int NB4 = (N + 3) / 4;          // 4 nodes (waves) per block
    const int gemmRows = (N + 63) / 64;   // 782

    // --- layer 1: h1 = relu(agg(x@W1) + b1) ---
    gemm_mfma_kernel<128><<<dim3(gemmRows, 2), 256, 0, stream>>>(x, W1thi, W1tlo, dis, bufT, N);
    aggregate_panel_kernel<8, true><<<NB4 * 8, 256, 0, stream>>>(
        rowoff, csr_src, dis, bufT, b1, bufH, N);

    // --- layer 2: h2 = relu(agg(h1@Wh) + bh) ---
    gemm_mfma_kernel<128><<<dim3(gemmRows, 2), 256, 0, stream>>>(bufH, Whthi, Whtlo, dis, bufT, N);
    aggregate_panel_kernel<8, true><<<NB4 * 8, 256, 0, stream>>>(
        rowoff, csr_src, dis, bufT, bh, bufH, N);

    // --- layer 3: h3 = agg(h2@W2) + b2 (fp32 into d_out) ---
    gemm_mfma_kernel<64><<<dim3(gemmRows, 1), 256, 0, stream>>>(bufH, W2thi, W2tlo, dis, bufT, N);
    aggregate_panel_kernel<4, false><<<NB4 * 4, 256, 0, stream>>>(
        rowoff, csr_src, dis, bufT, b2, hout, N);

    // --- head: out = h3 @ Wout + bout ---
    head_kernel<<<((size_t)N * 64 + 255) / 256, 256, 0, stream>>>(hout, Wout, bout, out, N);
}

// Round 11
// 344.836 us; speedup vs baseline: 1.3877x; 1.3877x over previous
//
#include <hip/hip_runtime.h>
#include <hip/hip_bf16.h>

// GCN: 3x GCNConv (sym-norm, self-loops) + linear head.
// N=50000 nodes, E=800000 edges, F: 128 -> 128 -> 128 -> 64 -> 1.
// Round 11: panel gather, granularity fixed. Round 10 proved XCD-panel
// locality (FETCH 113 -> 20 MB) but 16-col panels were instruction-bound
// (VALU 54%, 119 us: 8x replicated prologue + mostly-masked lanes).
// Now: 4 panels x 32 cols (3.2 MB per-XCD set, fits 4 MB L2; panel =
// blockIdx&3 -> XCDs {p,p+4}). Wave = (node-pair, panel): quarter-waves
// (16 lanes x ushort2 = 64 B row) take even/odd edges of n0/n1 -> 4 rows
// in flight (8 with unroll-2); one shfl_xor(16) reduce; prologue 4x not 8x.
// gemm<128> writes 32-col panels; F=64 layer + fused head = round-9 form.
// CSR build + gemm core unchanged.

#define N_NODES 50000
#define N_EDGES 800000
#define NBUCK 196          // ceil(N/256) coarse buckets (dst>>8)
#define GB 196             // edge-chunk blocks
#define EPB 4096           // edges per block (GB*EPB >= E)

typedef __attribute__((ext_vector_type(8))) short short8;   // 8 bf16 = 4 VGPR
typedef __attribute__((ext_vector_type(4))) float f32x4;    // MFMA C/D

static __device__ __forceinline__ unsigned short f2bf(float f) {
    __hip_bfloat16 h = __float2bfloat16(f);  // RNE
    return *reinterpret_cast<unsigned short*>(&h);
}
static __device__ __forceinline__ float bf2f(unsigned short u) {
    return __uint_as_float(((unsigned)u) << 16);  // exact
}

// ---------- CSR build: two-level counting sort ----------

__global__ __launch_bounds__(256) void hist_kernel(const int* __restrict__ dstv,
                                                   int* __restrict__ H, int nE) {
    __shared__ int h[NBUCK];
    for (int i = threadIdx.x; i < NBUCK; i += 256) h[i] = 0;
    __syncthreads();
    int base = blockIdx.x * EPB;
#pragma unroll
    for (int i = 0; i < EPB / 256; ++i) {
        int e = base + i * 256 + threadIdx.x;
        if (e < nE) atomicAdd(&h[dstv[e] >> 8], 1);
    }
    __syncthreads();
    for (int i = threadIdx.x; i < NBUCK; i += 256)
        H[i * GB + blockIdx.x] = h[i];   // bucket-major
}

__global__ __launch_bounds__(256) void scan1_kernel(int* __restrict__ H,
                                                    int* __restrict__ bsum) {
    __shared__ int s[256];
    int t = threadIdx.x;
    int k = blockIdx.x;
    int v = (t < GB) ? H[k * GB + t] : 0;
    s[t] = v;
    __syncthreads();
    for (int off = 1; off < 256; off <<= 1) {
        int u = (t >= off) ? s[t - off] : 0;
        __syncthreads();
        s[t] += u;
        __syncthreads();
    }
    if (t < GB) H[k * GB + t] = s[t] - v;  // local exclusive
    if (t == 255) bsum[k] = s[255];
}

__global__ __launch_bounds__(256) void scan2_kernel(const int* __restrict__ bsum,
                                                    int* __restrict__ bstart,
                                                    int* __restrict__ rowoff_last) {
    __shared__ int s[256];
    int t = threadIdx.x;
    int v = (t < NBUCK) ? bsum[t] : 0;
    s[t] = v;
    __syncthreads();
    for (int off = 1; off < 256; off <<= 1) {
        int u = (t >= off) ? s[t - off] : 0;
        __syncthreads();
        s[t] += u;
        __syncthreads();
    }
    if (t < NBUCK) bstart[t] = s[t] - v;  // exclusive
    if (t == 0) {
        bstart[NBUCK] = N_EDGES;
        *rowoff_last = N_EDGES;
    }
}

__global__ __launch_bounds__(256) void partition_kernel(const int* __restrict__ srcv,
                                                        const int* __restrict__ dstv,
                                                        const int* __restrict__ H,
                                                        const int* __restrict__ bstart,
                                                        int2* __restrict__ P, int nE) {
    __shared__ int cur[NBUCK];
    for (int i = threadIdx.x; i < NBUCK; i += 256)
        cur[i] = bstart[i] + H[i * GB + blockIdx.x];
    __syncthreads();
    int base = blockIdx.x * EPB;
#pragma unroll
    for (int i = 0; i < EPB / 256; ++i) {
        int e = base + i * 256 + threadIdx.x;
        if (e < nE) {
            int d = dstv[e];
            int sv = srcv[e];
            int pos = atomicAdd(&cur[d >> 8], 1);
            P[pos] = make_int2(sv, d);
        }
    }
}

__global__ __launch_bounds__(256) void bucket_csr_kernel(const int2* __restrict__ P,
                                                         const int* __restrict__ bstart,
                                                         int* __restrict__ rowoff,
                                                         float* __restrict__ dis,
                                                         int* __restrict__ csr_src, int n) {
    __shared__ int cnt[256];
    __shared__ int s[256];
    __shared__ int cur[256];
    int t = threadIdx.x;
    int k = blockIdx.x;
    int ebeg = bstart[k], eend = bstart[k + 1];
    cnt[t] = 0;
    __syncthreads();
    for (int e = ebeg + t; e < eend; e += 256)
        atomicAdd(&cnt[P[e].y & 255], 1);
    __syncthreads();
    int myc = cnt[t];
    s[t] = myc;
    __syncthreads();
    for (int off = 1; off < 256; off <<= 1) {
        int v = (t >= off) ? s[t - off] : 0;
        __syncthreads();
        s[t] += v;
        __syncthreads();
    }
    int excl = s[t] - myc;
    int node = (k << 8) + t;
    if (node < n) {
        rowoff[node] = ebeg + excl;
        dis[node] = rsqrtf((float)(myc + 1));  // +1 self-loop
    }
    cur[t] = ebeg + excl;
    __syncthreads();
    for (int e = ebeg + t; e < eend; e += 256) {
        int2 p = P[e];
        int pos = atomicAdd(&cur[p.y & 255], 1);
        csr_src[pos] = p.x;
    }
}

// ---------- W prep (fused): W -> transposed bf16 hi/lo [col][k] ----------
__global__ __launch_bounds__(256) void wprep_all_kernel(
    const float* __restrict__ W1, const float* __restrict__ Wh, const float* __restrict__ W2,
    unsigned short* __restrict__ W1hi, unsigned short* __restrict__ W1lo,
    unsigned short* __restrict__ Whhi, unsigned short* __restrict__ Whlo,
    unsigned short* __restrict__ W2hi, unsigned short* __restrict__ W2lo) {
    int t = blockIdx.x * 256 + threadIdx.x;
    const float* W;
    unsigned short *Hi, *Lo;
    int nout, lt;
    if (t < 16384)      { W = W1; Hi = W1hi; Lo = W1lo; nout = 128; lt = t; }
    else if (t < 32768) { W = Wh; Hi = Whhi; Lo = Whlo; nout = 128; lt = t - 16384; }
    else if (t < 40960) { W = W2; Hi = W2hi; Lo = W2lo; nout = 64;  lt = t - 32768; }
    else return;
    int col = lt % nout, k = lt / nout;
    float v = W[lt];                       // coalesced (lt == k*nout+col)
    unsigned short hi = f2bf(v);
    unsigned short lo = f2bf(v - bf2f(hi));
    Hi[(size_t)col * 128 + k] = hi;
    Lo[(size_t)col * 128 + k] = lo;
}

// ---------- MFMA GEMM: C[r] = bf16((A[r] @ W) * scale[r]) ----------
// Block = 64 rows x 64 cols, 4 waves. B hi/lo in registers, A hi/lo in LDS.
// PANEL: output as 32-col panels [p][N][32]; else row-major [N][NOUT].
template <int NOUT, bool PANEL>
__global__ __launch_bounds__(256) void gemm_mfma_kernel(
    const float* __restrict__ A,
    const unsigned short* __restrict__ Wthi,  // [NOUT][128] bf16
    const unsigned short* __restrict__ Wtlo,
    const float* __restrict__ scale,
    unsigned short* __restrict__ C, int M) {
    constexpr int LDK = 136;  // shorts; 16 B-aligned frags, banks spread
    __shared__ unsigned short sAhi[64 * LDK];
    __shared__ unsigned short sAlo[64 * LDK];

    int tid = threadIdx.x;
    int w = tid >> 6, lane = tid & 63;
    int quad = lane >> 4, m = lane & 15;
    int Rbase = blockIdx.x * 64;
    int Cbase = blockIdx.y * 64;
    int r0 = (w & 1) * 32, c0 = (w >> 1) * 32;

    // B-frags to registers (once per wave): [ks][grp], grp = col 16-group
    short8 bh[4][2], bl[4][2];
#pragma unroll
    for (int ks = 0; ks < 4; ++ks)
#pragma unroll
        for (int g = 0; g < 2; ++g) {
            size_t off = (size_t)(Cbase + c0 + g * 16 + m) * 128 + ks * 32 + quad * 8;
            bh[ks][g] = *(const short8*)(Wthi + off);
            bl[ks][g] = *(const short8*)(Wtlo + off);
        }

    // stage A: 64 rows x 128 fp32 -> hi/lo bf16 in LDS
    for (int i = tid; i < 64 * 32; i += 256) {
        int r = i >> 5, c4 = i & 31;
        int row = Rbase + r;
        float4 v = make_float4(0.f, 0.f, 0.f, 0.f);
        if (row < M) v = ((const float4*)(A + (size_t)row * 128))[c4];
        ushort4 hi, lo;
        hi.x = f2bf(v.x); lo.x = f2bf(v.x - bf2f(hi.x));
        hi.y = f2bf(v.y); lo.y = f2bf(v.y - bf2f(hi.y));
        hi.z = f2bf(v.z); lo.z = f2bf(v.z - bf2f(hi.z));
        hi.w = f2bf(v.w); lo.w = f2bf(v.w - bf2f(hi.w));
        *(ushort4*)(sAhi + r * LDK + c4 * 4) = hi;
        *(ushort4*)(sAlo + r * LDK + c4 * 4) = lo;
    }
    __syncthreads();

    f32x4 z = {0.f, 0.f, 0.f, 0.f};
    f32x4 acc00 = z, acc01 = z, acc10 = z, acc11 = z;

#pragma unroll
    for (int ks = 0; ks < 4; ++ks) {
        int kof = ks * 32 + quad * 8;
        short8 ah0 = *(const short8*)(sAhi + (r0 + m) * LDK + kof);
        short8 ah1 = *(const short8*)(sAhi + (r0 + 16 + m) * LDK + kof);
        short8 al0 = *(const short8*)(sAlo + (r0 + m) * LDK + kof);
        short8 al1 = *(const short8*)(sAlo + (r0 + 16 + m) * LDK + kof);
        acc00 = __builtin_amdgcn_mfma_f32_16x16x32_bf16(ah0, bh[ks][0], acc00, 0, 0, 0);
        acc01 = __builtin_amdgcn_mfma_f32_16x16x32_bf16(ah0, bh[ks][1], acc01, 0, 0, 0);
        acc10 = __builtin_amdgcn_mfma_f32_16x16x32_bf16(ah1, bh[ks][0], acc10, 0, 0, 0);
        acc11 = __builtin_amdgcn_mfma_f32_16x16x32_bf16(ah1, bh[ks][1], acc11, 0, 0, 0);
        acc00 = __builtin_amdgcn_mfma_f32_16x16x32_bf16(ah0, bl[ks][0], acc00, 0, 0, 0);
        acc01 = __builtin_amdgcn_mfma_f32_16x16x32_bf16(ah0, bl[ks][1], acc01, 0, 0, 0);
        acc10 = __builtin_amdgcn_mfma_f32_16x16x32_bf16(ah1, bl[ks][0], acc10, 0, 0, 0);
        acc11 = __builtin_amdgcn_mfma_f32_16x16x32_bf16(ah1, bl[ks][1], acc11, 0, 0, 0);
        acc00 = __builtin_amdgcn_mfma_f32_16x16x32_bf16(al0, bh[ks][0], acc00, 0, 0, 0);
        acc01 = __builtin_amdgcn_mfma_f32_16x16x32_bf16(al0, bh[ks][1], acc01, 0, 0, 0);
        acc10 = __builtin_amdgcn_mfma_f32_16x16x32_bf16(al1, bh[ks][0], acc10, 0, 0, 0);
        acc11 = __builtin_amdgcn_mfma_f32_16x16x32_bf16(al1, bh[ks][1], acc11, 0, 0, 0);
    }

    // epilogue: C/D layout col = lane&15 (m), row = quad*4 + reg
#pragma unroll
    for (int reg = 0; reg < 4; ++reg) {
        int row0g = Rbase + r0 + quad * 4 + reg;
        int row1g = row0g + 16;
        if (PANEL) {
            // 32-col panel p = (Cbase+c0)/32; in-panel col = g*16 + m
            size_t pbase = (size_t)((Cbase + c0) >> 5) * M * 32;
            if (row0g < M) {
                float sc = scale[row0g];
                C[pbase + (size_t)row0g * 32 + m]      = f2bf(acc00[reg] * sc);
                C[pbase + (size_t)row0g * 32 + 16 + m] = f2bf(acc01[reg] * sc);
            }
            if (row1g < M) {
                float sc = scale[row1g];
                C[pbase + (size_t)row1g * 32 + m]      = f2bf(acc10[reg] * sc);
                C[pbase + (size_t)row1g * 32 + 16 + m] = f2bf(acc11[reg] * sc);
            }
        } else {
            if (row0g < M) {
                float sc = scale[row0g];
                C[(size_t)row0g * NOUT + Cbase + c0 + m]      = f2bf(acc00[reg] * sc);
                C[(size_t)row0g * NOUT + Cbase + c0 + 16 + m] = f2bf(acc01[reg] * sc);
            }
            if (row1g < M) {
                float sc = scale[row1g];
                C[(size_t)row1g * NOUT + Cbase + c0 + m]      = f2bf(acc10[reg] * sc);
                C[(size_t)row1g * NOUT + Cbase + c0 + 16 + m] = f2bf(acc11[reg] * sc);
            }
        }
    }
}

// ---------- Panel gather aggregation (F=128, 4 panels x 32 cols) ----------
// Block = 4 waves, all on panel p = blockIdx&3 (XCDs {p,p+4} via round-robin).
// Wave = node pair; quarter-waves (16 lanes x ushort2 = 64 B row):
// q0/q1 = even/odd edges of n0, q2/q3 = of n1; shfl_xor(16) combines.
__global__ __launch_bounds__(256) void aggregate128_panel_kernel(
    const int* __restrict__ rowoff, const int* __restrict__ csr_src,
    const float* __restrict__ dis, const unsigned short* __restrict__ tp,
    const float* __restrict__ bias, float* __restrict__ hout, int n) {
    int p = blockIdx.x & 3;
    int pair = (blockIdx.x >> 2) * 4 + (threadIdx.x >> 6);
    int n0 = pair * 2;
    if (n0 >= n) return;
    int n1 = n0 + 1;
    bool has1 = (n1 < n);
    int lane = threadIdx.x & 63;
    int q = lane >> 4, lc = lane & 15;
    bool isN1 = (q >= 2);
    int par = q & 1;
    const unsigned short* panel = tp + (size_t)p * n * 32;

    int node = isN1 ? n1 : n0;
    bool active = !isN1 || has1;
    float ax = 0.f, ay = 0.f;

    if (active) {
        // self-loop on q0 (n0) and q2 (n1)
        if (par == 0) {
            ushort2 u = *((const ushort2*)(panel + (size_t)node * 32) + lc);
            ax = bf2f(u.x);
            ay = bf2f(u.y);
        }
        int beg = rowoff[node], end = rowoff[node + 1];
        int i = beg + par;
        for (; i + 2 < end; i += 4) {  // 2 rows in flight per quarter
            int s0 = csr_src[i], s1 = csr_src[i + 2];
            ushort2 u0 = *((const ushort2*)(panel + (size_t)s0 * 32) + lc);
            ushort2 u1 = *((const ushort2*)(panel + (size_t)s1 * 32) + lc);
            ax += bf2f(u0.x) + bf2f(u1.x);
            ay += bf2f(u0.y) + bf2f(u1.y);
        }
        for (; i < end; i += 2) {
            ushort2 u = *((const ushort2*)(panel + (size_t)csr_src[i] * 32) + lc);
            ax += bf2f(u.x);
            ay += bf2f(u.y);
        }
    }
    // combine even/odd quarters (q0<-q1, q2<-q3)
    ax += __shfl_xor(ax, 16);
    ay += __shfl_xor(ay, 16);

    if (par == 0 && active) {
        float dd = dis[node];
        float2 b = *((const float2*)(bias + p * 32) + lc);
        float2 r;
        r.x = fmaxf(ax * dd + b.x, 0.f);
        r.y = fmaxf(ay * dd + b.y, 0.f);
        *((float2*)(hout + (size_t)node * 128 + p * 32) + lc) = r;
    }
}

// F=64 + fused head (row-major tp). 32 lanes x ushort2 = one 128 B row/half.
__global__ __launch_bounds__(256) void aggregate64_head_kernel(
    const int* __restrict__ rowoff, const int* __restrict__ csr_src,
    const float* __restrict__ dis, const unsigned short* __restrict__ tp,
    const float* __restrict__ bias, const float* __restrict__ Wout,
    const float* __restrict__ bout, float* __restrict__ hout,
    float* __restrict__ out, int n) {
    int wid = (blockIdx.x * 256 + threadIdx.x) >> 6;
    int lane = threadIdx.x & 63;
    int h = lane >> 5, lc = lane & 31;
    int n0 = wid * 2;
    if (n0 >= n) return;
    int n1 = n0 + 1;
    bool has1 = (n1 < n);

    float a0[2] = {0.f, 0.f};
    float a1[2] = {0.f, 0.f};

#define ROW64(node) (*((const ushort2*)(tp + (size_t)(node) * 64) + lc))
#define ACC2(a, u) { a[0] += bf2f(u.x); a[1] += bf2f(u.y); }

    if (h == 0) { ushort2 u = ROW64(n0); ACC2(a0, u); }
    else if (has1) { ushort2 u = ROW64(n1); ACC2(a1, u); }

    int mid = rowoff[n0 + 1];
    int i0 = rowoff[n0] + h;
    int i1 = mid + h;
    int end1 = has1 ? rowoff[n1 + 1] : mid;

    while (i0 + 2 < mid && i1 + 2 < end1) {
        int s0a = csr_src[i0], s0b = csr_src[i0 + 2];
        int s1a = csr_src[i1], s1b = csr_src[i1 + 2];
        ushort2 u0 = ROW64(s0a), u1 = ROW64(s0b);
        ushort2 v0 = ROW64(s1a), v1 = ROW64(s1b);
        ACC2(a0, u0); ACC2(a0, u1);
        ACC2(a1, v0); ACC2(a1, v1);
        i0 += 4; i1 += 4;
    }
    for (; i0 < mid; i0 += 2) { ushort2 u = ROW64(csr_src[i0]); ACC2(a0, u); }
    for (; i1 < end1; i1 += 2) { ushort2 v = ROW64(csr_src[i1]); ACC2(a1, v); }
#undef ROW64

#pragma unroll
    for (int j = 0; j < 2; ++j) {
        a0[j] += __shfl_xor(a0[j], 32);
        a1[j] += __shfl_xor(a1[j], 32);
    }

    int node = h ? n1 : n0;
    float* ap = h ? a1 : a0;
    bool valid = (h == 0) || has1;
    float2 hv = make_float2(0.f, 0.f);
    if (valid) {
        float dd = dis[node];
        float2 b = ((const float2*)bias)[lc];
        hv.x = ap[0] * dd + b.x;
        hv.y = ap[1] * dd + b.y;
        ((float2*)(hout + (size_t)node * 64))[lc] = hv;
    }
    float2 wv = ((const float2*)Wout)[lc];
    float p = valid ? (hv.x * wv.x + hv.y * wv.y) : 0.f;
#pragma unroll
    for (int off = 16; off > 0; off >>= 1) p += __shfl_down(p, off);
    if (lc == 0 && valid) out[node] = p + bout[0];
}

extern "C" void kernel_launch(void* const* d_in, const int* in_sizes, int n_in,
                              void* d_out, int out_size, void* d_ws, size_t ws_size,
                              hipStream_t stream) {
    const float* x    = (const float*)d_in[0];
    const int*   ei   = (const int*)d_in[1];  // [2, E] flat: src then dst
    const float* W1   = (const float*)d_in[2];
    const float* b1   = (const float*)d_in[3];
    const float* Wh   = (const float*)d_in[4];
    const float* bh   = (const float*)d_in[5];
    const float* W2   = (const float*)d_in[6];
    const float* b2   = (const float*)d_in[7];
    const float* Wout = (const float*)d_in[8];
    const float* bout = (const float*)d_in[9];

    const int N = N_NODES;
    const int E = N_EDGES;
    const int* srcv = ei;
    const int* dstv = ei + E;

    float* out  = (float*)d_out;            // [N]
    float* hout = (float*)d_out + N;        // [N x 64]

    char* ws = (char*)d_ws;
    int*   H       = (int*)ws;                          ws += sizeof(int) * NBUCK * GB;
    int*   bsum    = (int*)ws;                          ws += sizeof(int) * NBUCK;
    int*   bstart  = (int*)ws;                          ws += sizeof(int) * (NBUCK + 1);
    int*   rowoff  = (int*)ws;                          ws += sizeof(int) * (N + 1);
    int2*  P       = (int2*)ws;                         ws += sizeof(int2) * E;
    int*   csr_src = (int*)ws;                          ws += sizeof(int) * E;
    float* dis     = (float*)ws;                        ws += sizeof(float) * N;
    unsigned short* W1thi = (unsigned short*)ws;        ws += sizeof(unsigned short) * 128 * 128;
    unsigned short* W1tlo = (unsigned short*)ws;        ws += sizeof(unsigned short) * 128 * 128;
    unsigned short* Whthi = (unsigned short*)ws;        ws += sizeof(unsigned short) * 128 * 128;
    unsigned short* Whtlo = (unsigned short*)ws;        ws += sizeof(unsigned short) * 128 * 128;
    unsigned short* W2thi = (unsigned short*)ws;        ws += sizeof(unsigned short) * 64 * 128;
    unsigned short* W2tlo = (unsigned short*)ws;        ws += sizeof(unsigned short) * 64 * 128;
    unsigned short* bufT  = (unsigned short*)ws;        ws += sizeof(unsigned short) * (size_t)N * 128;
    float* bufH    = (float*)ws;                        // N*128 fp32

    // --- W prep (fused, bf16 hi/lo transposed) ---
    wprep_all_kernel<<<160, 256, 0, stream>>>(W1, Wh, W2, W1thi, W1tlo, Whthi, Whtlo, W2thi, W2tlo);

    // --- CSR build (two-level counting sort, hierarchical scan) ---
    hist_kernel<<<GB, 256, 0, stream>>>(dstv, H, E);
    scan1_kernel<<<NBUCK, 256, 0, stream>>>(H, bsum);
    scan2_kernel<<<1, 256, 0, stream>>>(bsum, bstart, rowoff + N);
    partition_kernel<<<GB, 256, 0, stream>>>(srcv, dstv, H, bstart, P, E);
    bucket_csr_kernel<<<NBUCK, 256, 0, stream>>>(P, bstart, rowoff, dis, csr_src, N);

    const int gemmRows = (N + 63) / 64;                  // 782
    const int aggPBlocks = ((N + 7) / 8) * 4;            // 8 nodes/block x 4 panels
    const int agg64Blocks = ((N + 1) / 2 * 64 + 255) / 256;

    // --- layer 1: h1 = relu(agg(x@W1) + b1) ---
    gemm_mfma_kernel<128, true><<<dim3(gemmRows, 2), 256, 0, stream>>>(x, W1thi, W1tlo, dis, bufT, N);
    aggregate128_panel_kernel<<<aggPBlocks, 256, 0, stream>>>(
        rowoff, csr_src, dis, bufT, b1, bufH, N);

    // --- layer 2: h2 = relu(agg(h1@Wh) + bh) ---
    gemm_mfma_kernel<128, true><<<dim3(gemmRows, 2), 256, 0, stream>>>(bufH, Whthi, Whtlo, dis, bufT, N);
    aggregate128_panel_kernel<<<aggPBlocks, 256, 0, stream>>>(
        rowoff, csr_src, dis, bufT, bh, bufH, N);

    // --- layer 3 + head: h3 = agg(h2@W2) + b2 ; out = h3@Wout + bout ---
    gemm_mfma_kernel<64, false><<<dim3(gemmRows, 1), 256, 0, stream>>>(bufH, W2thi, W2tlo, dis, bufT, N);
    aggregate64_head_kernel<<<agg64Blocks, 256, 0, stream>>>(
        rowoff, csr_src, dis, bufT, b2, Wout, bout, hout, out, N);
}